// Round 3
// baseline (950.196 us; speedup 1.0000x reference)
//
#include <hip/hip_runtime.h>
#include <math.h>

#define NEG_SLOPE 0.2f

// round-to-nearest-even fp32 -> packed 2x bf16 (x in low half, y in high half)
__device__ __forceinline__ unsigned pack_bf2(float x, float y) {
    unsigned ux = __float_as_uint(x), uy = __float_as_uint(y);
    ux = (ux + 0x7fffu + ((ux >> 16) & 1u)) >> 16;
    uy = (uy + 0x7fffu + ((uy >> 16) & 1u)) & 0xffff0000u;
    return ux | uy;
}

// ---------------- CSR build ----------------

__global__ void k_hist(const int* __restrict__ dst, int* __restrict__ deg, int E) {
    int e = blockIdx.x * 256 + threadIdx.x;
    if (e < E) atomicAdd(&deg[dst[e]], 1);
}

// block scans 2048 elements (256 threads x 8)
__global__ void k_scan1(const int* __restrict__ in, int* __restrict__ out,
                        int* __restrict__ bsum, int n) {
    __shared__ int sd[256];
    int t = threadIdx.x;
    int base = blockIdx.x * 2048 + t * 8;
    int v[8];
#pragma unroll
    for (int i = 0; i < 8; i++) { int idx = base + i; v[i] = (idx < n) ? in[idx] : 0; }
#pragma unroll
    for (int i = 1; i < 8; i++) v[i] += v[i - 1];
    sd[t] = v[7];
    __syncthreads();
    for (int s = 1; s < 256; s <<= 1) {
        int x = (t >= s) ? sd[t - s] : 0;
        __syncthreads();
        sd[t] += x;
        __syncthreads();
    }
    int off = (t > 0) ? sd[t - 1] : 0;
#pragma unroll
    for (int i = 0; i < 8; i++) {
        int idx = base + i;
        if (idx < n) out[idx] = off + (i > 0 ? v[i - 1] : 0);
    }
    if (t == 255) bsum[blockIdx.x] = sd[255];
}

__global__ void k_scan2(int* __restrict__ bsum, int nb) {
    __shared__ int sd[256];
    int t = threadIdx.x;
    sd[t] = (t < nb) ? bsum[t] : 0;
    __syncthreads();
    for (int s = 1; s < 256; s <<= 1) {
        int x = (t >= s) ? sd[t - s] : 0;
        __syncthreads();
        sd[t] += x;
        __syncthreads();
    }
    if (t < nb) bsum[t] = (t > 0) ? sd[t - 1] : 0;
}

__global__ void k_scan3(int* __restrict__ out, int* __restrict__ cursor,
                        const int* __restrict__ bsum, int n) {
    int idx = blockIdx.x * 256 + threadIdx.x;
    if (idx < n) {
        int v = out[idx] + bsum[idx >> 11];
        out[idx] = v;
        cursor[idx] = v;
    }
}

__global__ void k_scatter(const int* __restrict__ src, const int* __restrict__ dst,
                          int* __restrict__ cursor, int* __restrict__ csrc, int E) {
    int e = blockIdx.x * 256 + threadIdx.x;
    if (e < E) {
        int d = dst[e];
        int p = atomicAdd(&cursor[d], 1);
        csrc[p] = src[e];
    }
}

// ---------------- GEMM + el/er epilogue ----------------
// f = A(Mx128) @ W(128x128), 4x4 register blocking, double-buffered Ws:
// W chunk kc+1 is global-loaded into registers before computing chunk kc,
// stored to the alternate LDS buffer after compute -> one barrier per kc,
// global latency hidden behind 32 kk iters (~1024 VALU cyc).
// F is written as packed bf16 (aggregation gathers are BW-bound; el/er and
// all accumulation stay fp32).
__global__ __launch_bounds__(256) void k_gemm(
    const float* __restrict__ A, const float* __restrict__ W,
    const float* __restrict__ alv, const float* __restrict__ arv,
    unsigned* __restrict__ Fb, float* __restrict__ el, float* __restrict__ er, int M) {
    __shared__ float As[32][132];     // +4 pad
    __shared__ float Ws[2][32][128];  // double buffer
    int t = threadIdx.x;
    int row0 = blockIdx.x * 32;

    // stage A tile (32x128) + W chunk 0
    float4 av[4], wv[4];
#pragma unroll
    for (int c = 0; c < 4; c++) {
        int q = t + c * 256;
        int r = q >> 5, c4 = q & 31;
        av[c] = make_float4(0.f, 0.f, 0.f, 0.f);
        if (row0 + r < M) av[c] = *(const float4*)&A[(size_t)(row0 + r) * 128 + c4 * 4];
        wv[c] = *(const float4*)&W[(size_t)r * 128 + c4 * 4];
    }
#pragma unroll
    for (int c = 0; c < 4; c++) {
        int q = t + c * 256;
        int r = q >> 5, c4 = q & 31;
        *(float4*)&As[r][c4 * 4] = av[c];
        *(float4*)&Ws[0][r][c4 * 4] = wv[c];
    }
    __syncthreads();

    int rowg = t >> 5, colg = t & 31;
    float4 acc[4];
#pragma unroll
    for (int r = 0; r < 4; r++) acc[r] = make_float4(0.f, 0.f, 0.f, 0.f);

    for (int kc = 0; kc < 4; kc++) {
        if (kc < 3) {
#pragma unroll
            for (int c = 0; c < 4; c++) {
                int q = t + c * 256;
                int r = q >> 5, c4 = q & 31;
                wv[c] = *(const float4*)&W[(size_t)((kc + 1) * 32 + r) * 128 + c4 * 4];
            }
        }
        const float(*Wb)[128] = Ws[kc & 1];
#pragma unroll
        for (int kk = 0; kk < 32; kk++) {
            float4 w = *(const float4*)&Wb[kk][colg * 4];
            float a0 = As[rowg * 4 + 0][kc * 32 + kk];
            float a1 = As[rowg * 4 + 1][kc * 32 + kk];
            float a2 = As[rowg * 4 + 2][kc * 32 + kk];
            float a3 = As[rowg * 4 + 3][kc * 32 + kk];
            acc[0].x += a0 * w.x; acc[0].y += a0 * w.y; acc[0].z += a0 * w.z; acc[0].w += a0 * w.w;
            acc[1].x += a1 * w.x; acc[1].y += a1 * w.y; acc[1].z += a1 * w.z; acc[1].w += a1 * w.w;
            acc[2].x += a2 * w.x; acc[2].y += a2 * w.y; acc[2].z += a2 * w.z; acc[2].w += a2 * w.w;
            acc[3].x += a3 * w.x; acc[3].y += a3 * w.y; acc[3].z += a3 * w.z; acc[3].w += a3 * w.w;
        }
        if (kc < 3) {
#pragma unroll
            for (int c = 0; c < 4; c++) {
                int q = t + c * 256;
                int r = q >> 5, c4 = q & 31;
                *(float4*)&Ws[(kc + 1) & 1][r][c4 * 4] = wv[c];
            }
            __syncthreads();
        }
    }

    // epilogue: bf16 F write (coalesced 8B/lane) + fp32 el/er
    float4 a4 = *(const float4*)&alv[colg * 4];
    float4 r4 = *(const float4*)&arv[colg * 4];
    float pl[4], pr[4];
#pragma unroll
    for (int r = 0; r < 4; r++) {
        int grow = row0 + rowg * 4 + r;
        if (grow < M) {
            uint2 pk;
            pk.x = pack_bf2(acc[r].x, acc[r].y);
            pk.y = pack_bf2(acc[r].z, acc[r].w);
            *(uint2*)&Fb[(size_t)grow * 64 + colg * 2] = pk;
        }
        pl[r] = acc[r].x * a4.x + acc[r].y * a4.y + acc[r].z * a4.z + acc[r].w * a4.w;
        pr[r] = acc[r].x * r4.x + acc[r].y * r4.y + acc[r].z * r4.z + acc[r].w * r4.w;
    }
#pragma unroll
    for (int off = 1; off < 8; off <<= 1) {
#pragma unroll
        for (int r = 0; r < 4; r++) {
            pl[r] += __shfl_xor(pl[r], off, 64);
            pr[r] += __shfl_xor(pr[r], off, 64);
        }
    }
    if ((colg & 7) == 0) {
        int head = colg >> 3;
#pragma unroll
        for (int r = 0; r < 4; r++) {
            int grow = row0 + rowg * 4 + r;
            if (grow < M) {
                el[grow * 4 + head] = pl[r];
                er[grow * 4 + head] = pr[r];
            }
        }
    }
}

// ---------------- aggregation (wave per node, lanes over features) ----------------
// F gathered as packed bf16 (4B/lane -> 256B/edge, half the fp32 traffic);
// unpack = 1 shift + 1 and; accumulate fp32. 8-edge unroll keeps 16 gathers
// in flight. No max-subtraction (e scale ~ +-2, exp safe; softmax shift-inv).
__global__ __launch_bounds__(256) void k_aggr(
    const int* __restrict__ rowstart, const int* __restrict__ deg,
    const int* __restrict__ csrc, const float* __restrict__ el,
    const float* __restrict__ er, const unsigned* __restrict__ Fb,
    float* __restrict__ out, int N) {
    int w = blockIdx.x * 4 + (threadIdx.x >> 6);
    int lane = threadIdx.x & 63;
    if (w >= N) return;
    int h = lane >> 4;
    int start = rowstart[w], dg = deg[w];
    float er_h = er[w * 4 + h];
    float s_acc = 0.f, a0 = 0.f, a1 = 0.f;
    for (int j = 0; j < dg; j += 8) {
        int idx[8];
#pragma unroll
        for (int u = 0; u < 8; u++) {
            int jj = j + u;
            idx[u] = (jj < dg) ? csrc[start + jj] : -1;
        }
        unsigned fv[8];
        float ee[8];
#pragma unroll
        for (int u = 0; u < 8; u++) {
            int s = idx[u] < 0 ? 0 : idx[u];
            fv[u] = Fb[(size_t)s * 64 + lane];
            ee[u] = el[s * 4 + h];
        }
#pragma unroll
        for (int u = 0; u < 8; u++) {
            float e = ee[u] + er_h;
            e = e > 0.f ? e : NEG_SLOPE * e;
            float p = (idx[u] >= 0) ? __expf(e) : 0.f;
            s_acc += p;
            float f0 = __uint_as_float(fv[u] << 16);
            float f1 = __uint_as_float(fv[u] & 0xffff0000u);
            a0 += p * f0;
            a1 += p * f1;
        }
    }
    float inv = 1.f / (s_acc + 1e-9f);
    float2 o;
    o.x = fmaxf(a0 * inv, 0.f);
    o.y = fmaxf(a1 * inv, 0.f);
    ((float2*)out)[(size_t)w * 64 + lane] = o;
}

// ---------------- launch ----------------

extern "C" void kernel_launch(void* const* d_in, const int* in_sizes, int n_in,
                              void* d_out, int out_size, void* d_ws, size_t ws_size,
                              hipStream_t stream) {
    const float* x = (const float*)d_in[0];
    const int* ei = (const int*)d_in[1];
    int N = in_sizes[0] / 128;       // 100000
    int E = in_sizes[1] / 2;         // 1600000
    const int* src = ei;
    const int* dst = ei + E;
    const float* Wm[3] = {(const float*)d_in[2], (const float*)d_in[5], (const float*)d_in[8]};
    const float* al[3] = {(const float*)d_in[3], (const float*)d_in[6], (const float*)d_in[9]};
    const float* ar[3] = {(const float*)d_in[4], (const float*)d_in[7], (const float*)d_in[10]};

    // workspace carve (256B aligned)
    char* p = (char*)d_ws;
    auto carve = [&](size_t bytes) {
        char* r = p;
        p += (bytes + 255) & ~(size_t)255;
        return r;
    };
    unsigned* Fb    = (unsigned*)carve((size_t)N * 64 * 4);   // bf16 F: [N][128] packed
    float* H        = (float*)carve((size_t)N * 128 * 4);
    float* el       = (float*)carve((size_t)N * 4 * 4);
    float* er       = (float*)carve((size_t)N * 4 * 4);
    int* deg        = (int*)carve((size_t)N * 4);
    int* rowstart   = (int*)carve((size_t)N * 4);
    int* cursor     = (int*)carve((size_t)N * 4);
    int* csrc       = (int*)carve((size_t)E * 4);
    int* bsum       = (int*)carve(256 * 4);

    // ---- CSR build (once; reused by all 3 layers) ----
    hipMemsetAsync(deg, 0, (size_t)N * 4, stream);
    k_hist<<<(E + 255) / 256, 256, 0, stream>>>(dst, deg, E);
    int nb = (N + 2047) / 2048;
    k_scan1<<<nb, 256, 0, stream>>>(deg, rowstart, bsum, N);
    k_scan2<<<1, 256, 0, stream>>>(bsum, nb);
    k_scan3<<<(N + 255) / 256, 256, 0, stream>>>(rowstart, cursor, bsum, N);
    k_scatter<<<(E + 255) / 256, 256, 0, stream>>>(src, dst, cursor, csrc, E);

    // ---- 3 GAT layers ----
    const float* in = x;
    float* outs[3] = {(float*)d_out, H, (float*)d_out};  // d_out(h1) dead by the time layer2 writes
    for (int L = 0; L < 3; L++) {
        k_gemm<<<(N + 31) / 32, 256, 0, stream>>>(in, Wm[L], al[L], ar[L], Fb, el, er, N);
        k_aggr<<<(N + 3) / 4, 256, 0, stream>>>(rowstart, deg, csrc, el, er, Fb, outs[L], N);
        in = outs[L];
    }
}

// Round 4
// 753.965 us; speedup vs baseline: 1.2603x; 1.2603x over previous
//
#include <hip/hip_runtime.h>
#include <math.h>

#define NEG_SLOPE 0.2f

typedef __attribute__((ext_vector_type(8))) short short8;   // 8 bf16 = 4 VGPR (MFMA A/B frag)
typedef __attribute__((ext_vector_type(4))) float f32x4;    // MFMA C/D frag

__device__ __forceinline__ unsigned short bf16rne(float x) {
    unsigned u = __float_as_uint(x);
    u += 0x7fffu + ((u >> 16) & 1u);
    return (unsigned short)(u >> 16);
}
// pack two floats -> uint (x low16, y high16), RNE
__device__ __forceinline__ unsigned pack_bf2(float x, float y) {
    unsigned ux = __float_as_uint(x), uy = __float_as_uint(y);
    ux = (ux + 0x7fffu + ((ux >> 16) & 1u)) >> 16;
    uy = (uy + 0x7fffu + ((uy >> 16) & 1u)) & 0xffff0000u;
    return ux | uy;
}

// ---------------- CSR build ----------------

__global__ void k_hist(const int* __restrict__ dst, int* __restrict__ deg, int E) {
    int e = blockIdx.x * 256 + threadIdx.x;
    if (e < E) atomicAdd(&deg[dst[e]], 1);
}

__global__ void k_scan1(const int* __restrict__ in, int* __restrict__ out,
                        int* __restrict__ bsum, int n) {
    __shared__ int sd[256];
    int t = threadIdx.x;
    int base = blockIdx.x * 2048 + t * 8;
    int v[8];
#pragma unroll
    for (int i = 0; i < 8; i++) { int idx = base + i; v[i] = (idx < n) ? in[idx] : 0; }
#pragma unroll
    for (int i = 1; i < 8; i++) v[i] += v[i - 1];
    sd[t] = v[7];
    __syncthreads();
    for (int s = 1; s < 256; s <<= 1) {
        int x = (t >= s) ? sd[t - s] : 0;
        __syncthreads();
        sd[t] += x;
        __syncthreads();
    }
    int off = (t > 0) ? sd[t - 1] : 0;
#pragma unroll
    for (int i = 0; i < 8; i++) {
        int idx = base + i;
        if (idx < n) out[idx] = off + (i > 0 ? v[i - 1] : 0);
    }
    if (t == 255) bsum[blockIdx.x] = sd[255];
}

__global__ void k_scan2(int* __restrict__ bsum, int nb) {
    __shared__ int sd[256];
    int t = threadIdx.x;
    sd[t] = (t < nb) ? bsum[t] : 0;
    __syncthreads();
    for (int s = 1; s < 256; s <<= 1) {
        int x = (t >= s) ? sd[t - s] : 0;
        __syncthreads();
        sd[t] += x;
        __syncthreads();
    }
    if (t < nb) bsum[t] = (t > 0) ? sd[t - 1] : 0;
}

__global__ void k_scan3(int* __restrict__ out, int* __restrict__ cursor,
                        const int* __restrict__ bsum, int n) {
    int idx = blockIdx.x * 256 + threadIdx.x;
    if (idx < n) {
        int v = out[idx] + bsum[idx >> 11];
        out[idx] = v;
        cursor[idx] = v;
    }
}

__global__ void k_scatter(const int* __restrict__ src, const int* __restrict__ dst,
                          int* __restrict__ cursor, int* __restrict__ csrc, int E) {
    int e = blockIdx.x * 256 + threadIdx.x;
    if (e < E) {
        int d = dst[e];
        int p = atomicAdd(&cursor[d], 1);
        csrc[p] = src[e];
    }
}

// ---------------- prep: fp32 -> bf16 planes ----------------

// x [M][128] fp32 -> Xb bf16 plane (packed as uint pairs). 8 floats/thread.
__global__ void k_cvt(const float4* __restrict__ x, uint4* __restrict__ Xb, int n8) {
    int id = blockIdx.x * 256 + threadIdx.x;
    if (id >= n8) return;
    float4 a = x[id * 2], b = x[id * 2 + 1];
    uint4 o;
    o.x = pack_bf2(a.x, a.y);
    o.y = pack_bf2(a.z, a.w);
    o.z = pack_bf2(b.x, b.y);
    o.w = pack_bf2(b.z, b.w);
    Xb[id] = o;
}

// W [128 k][128 n] fp32 -> Wt bf16 [n][k] (transposed, k-contiguous for B-frags).
// 3 layers in one launch.
__global__ void k_prep_w(const float* __restrict__ w0, const float* __restrict__ w1,
                         const float* __restrict__ w2, unsigned short* __restrict__ Wt) {
    int id = blockIdx.x * 256 + threadIdx.x;           // 3*16384
    int layer = id >> 14, rem = id & 16383;
    int k = rem >> 7, n = rem & 127;
    const float* W = (layer == 0) ? w0 : (layer == 1) ? w1 : w2;
    Wt[layer * 16384 + n * 128 + k] = bf16rne(W[k * 128 + n]);
}

// ---------------- MFMA GEMM + el/er epilogue ----------------
// f = A(Mx128 bf16) @ W(128x128, as Wt[n][k] bf16). 16x16x32 bf16 MFMA
// (A/B/C layouts HW-verified per m89/m91). Block = 4 waves x 32 rows = 128 rows.
// No LDS staging for A/W: frags loaded straight from global (A rows private to
// the wave; Wt shared -> L1/L2-hot). Per wave: acc 2(m) x 8(n) frags = 64 VGPR,
// K-loop = 4 steps of k=32. Epilogue: C-frags -> LDS bf16 (per-wave region, no
// barrier) -> coalesced 16B global F stores + el/er dot with al/ar + lane-pair
// combine. mfma work is ~1us total; kernel is memory-bound (~55 MB).
__global__ __launch_bounds__(256) void k_gemm(
    const unsigned short* __restrict__ Ab,   // [M][128] bf16
    const unsigned short* __restrict__ Wt,   // [128 n][128 k] bf16
    const float* __restrict__ alv, const float* __restrict__ arv,
    unsigned short* __restrict__ Fb,         // [M][128] bf16
    float* __restrict__ el, float* __restrict__ er, int M) {
    __shared__ unsigned short cst[4][32][128];
    int t = threadIdx.x;
    int wv = t >> 6, l = t & 63;
    int l15 = l & 15, quad = l >> 4;
    int row0 = blockIdx.x * 128 + wv * 32;

    f32x4 acc[2][8];
#pragma unroll
    for (int mi = 0; mi < 2; mi++)
#pragma unroll
        for (int nt = 0; nt < 8; nt++)
            acc[mi][nt] = (f32x4){0.f, 0.f, 0.f, 0.f};

    int rA0 = min(row0 + l15, M - 1);
    int rA1 = min(row0 + 16 + l15, M - 1);
    const uint4* pA0 = (const uint4*)(Ab + (size_t)rA0 * 128) + quad;  // +ks*4 per step
    const uint4* pA1 = (const uint4*)(Ab + (size_t)rA1 * 128) + quad;
    const uint4* pW = (const uint4*)Wt;

#pragma unroll
    for (int ks = 0; ks < 4; ks++) {
        union { uint4 u; short8 s; } a0, a1, b[8];
        a0.u = pA0[ks * 4];
        a1.u = pA1[ks * 4];
#pragma unroll
        for (int nt = 0; nt < 8; nt++)
            b[nt].u = pW[(nt * 16 + l15) * 16 + quad + ks * 4];
#pragma unroll
        for (int nt = 0; nt < 8; nt++) {
            acc[0][nt] = __builtin_amdgcn_mfma_f32_16x16x32_bf16(a0.s, b[nt].s, acc[0][nt], 0, 0, 0);
            acc[1][nt] = __builtin_amdgcn_mfma_f32_16x16x32_bf16(a1.s, b[nt].s, acc[1][nt], 0, 0, 0);
        }
    }

    // C/D layout: col = lane&15, row = quad*4 + reg. Stage to LDS bf16.
#pragma unroll
    for (int mi = 0; mi < 2; mi++)
#pragma unroll
        for (int nt = 0; nt < 8; nt++)
#pragma unroll
            for (int r = 0; r < 4; r++)
                cst[wv][mi * 16 + quad * 4 + r][nt * 16 + l15] = bf16rne(acc[mi][nt][r]);
    // same-wave ds_write -> ds_read: lgkmcnt ordering only, no barrier needed.

    int rrow = l >> 1;            // 0..31
    int cb = (l & 1) * 64;        // col base: lane covers 64 cols of one row
    int grow = row0 + rrow;
    bool ok = grow < M;
    float pe[2] = {0.f, 0.f}, pr[2] = {0.f, 0.f};
#pragma unroll
    for (int i = 0; i < 8; i++) {
        uint4 v = *(const uint4*)&cst[wv][rrow][cb + i * 8];
        if (ok) ((uint4*)(Fb + (size_t)grow * 128 + cb))[i] = v;
        int hi = i >> 2;          // head-local index (2 heads per 64-col half)
        int c0 = cb + i * 8;
        unsigned uu[4] = {v.x, v.y, v.z, v.w};
#pragma unroll
        for (int q = 0; q < 4; q++) {
            float fa = __uint_as_float(uu[q] << 16);
            float fb = __uint_as_float(uu[q] & 0xffff0000u);
            pe[hi] += fa * alv[c0 + 2 * q] + fb * alv[c0 + 2 * q + 1];
            pr[hi] += fa * arv[c0 + 2 * q] + fb * arv[c0 + 2 * q + 1];
        }
    }
    // lane l and l^1 hold the two col-halves of the same row (heads 0,1 | 2,3)
    float qe0 = __shfl_xor(pe[0], 1, 64), qe1 = __shfl_xor(pe[1], 1, 64);
    float qr0 = __shfl_xor(pr[0], 1, 64), qr1 = __shfl_xor(pr[1], 1, 64);
    if (((l & 1) == 0) && ok) {
        *(float4*)&el[(size_t)grow * 4] = make_float4(pe[0], pe[1], qe0, qe1);
        *(float4*)&er[(size_t)grow * 4] = make_float4(pr[0], pr[1], qr0, qr1);
    }
}

// ---------------- aggregation (wave per node, software-pipelined) ----------------
// Ping-pong chunks of 8 edges: chunk j+1's csrc + gathers issued before chunk j
// is consumed -> gather latency hidden behind a full chunk of VALU. Tail edges
// folded into a masked last chunk (sentinel ee=-1e30 -> exp=0), so no serial
// tail. leaky_relu(x) = fmax(x, 0.2x). OUT_BF16: write packed-bf16 H for the
// next layer's GEMM; else fp32 to d_out.
template <int OUT_BF16>
__global__ __launch_bounds__(256) void k_aggr(
    const int* __restrict__ rowstart, const int* __restrict__ deg,
    const int* __restrict__ csrc, const float* __restrict__ el,
    const float* __restrict__ er, const unsigned* __restrict__ FbU,
    void* __restrict__ outp, int N) {
    int w = blockIdx.x * 4 + (threadIdx.x >> 6);
    int lane = threadIdx.x & 63;
    if (w >= N) return;
    int h = lane >> 4;
    int start = rowstart[w], dg = deg[w];
    float er_h = er[w * 4 + h];
    float s_acc = 0.f, a0 = 0.f, a1 = 0.f;

    auto loadc = [&](int j, int* idx, unsigned* fv, float* ee) {
        if (j + 8 <= dg) {
#pragma unroll
            for (int u = 0; u < 8; u++) idx[u] = csrc[start + j + u];
#pragma unroll
            for (int u = 0; u < 8; u++) {
                fv[u] = FbU[(size_t)idx[u] * 64 + lane];
                ee[u] = el[idx[u] * 4 + h];
            }
        } else {
            int lim = dg - j;  // >= 1
#pragma unroll
            for (int u = 0; u < 8; u++) idx[u] = csrc[start + j + min(u, lim - 1)];
#pragma unroll
            for (int u = 0; u < 8; u++) {
                fv[u] = FbU[(size_t)idx[u] * 64 + lane];
                ee[u] = (u < lim) ? el[idx[u] * 4 + h] : -1e30f;
            }
        }
    };
    auto consume = [&](const unsigned* fv, const float* ee) {
#pragma unroll
        for (int u = 0; u < 8; u++) {
            float e = ee[u] + er_h;
            e = fmaxf(e, NEG_SLOPE * e);
            float p = __expf(e);
            s_acc += p;
            a0 += p * __uint_as_float(fv[u] << 16);
            a1 += p * __uint_as_float(fv[u] & 0xffff0000u);
        }
    };

    int ncc = (dg + 7) >> 3;
    int i0[8], i1[8];
    unsigned f0[8], f1[8];
    float e0[8], e1[8];
    if (ncc > 0) {
        loadc(0, i0, f0, e0);
        for (int c = 1; c < ncc; c++) {
            if (c & 1) { loadc(c << 3, i1, f1, e1); consume(f0, e0); }
            else       { loadc(c << 3, i0, f0, e0); consume(f1, e1); }
        }
        if (ncc & 1) consume(f0, e0); else consume(f1, e1);
    }

    float inv = 1.f / (s_acc + 1e-9f);
    float o0 = fmaxf(a0 * inv, 0.f);
    float o1 = fmaxf(a1 * inv, 0.f);
    if (OUT_BF16) {
        ((unsigned*)outp)[(size_t)w * 64 + lane] = pack_bf2(o0, o1);
    } else {
        ((float2*)outp)[(size_t)w * 64 + lane] = make_float2(o0, o1);
    }
}

// ---------------- launch ----------------

extern "C" void kernel_launch(void* const* d_in, const int* in_sizes, int n_in,
                              void* d_out, int out_size, void* d_ws, size_t ws_size,
                              hipStream_t stream) {
    const float* x = (const float*)d_in[0];
    const int* ei = (const int*)d_in[1];
    int N = in_sizes[0] / 128;       // 100000
    int E = in_sizes[1] / 2;         // 1600000
    const int* src = ei;
    const int* dst = ei + E;
    const float* Wm[3] = {(const float*)d_in[2], (const float*)d_in[5], (const float*)d_in[8]};
    const float* al[3] = {(const float*)d_in[3], (const float*)d_in[6], (const float*)d_in[9]};
    const float* ar[3] = {(const float*)d_in[4], (const float*)d_in[7], (const float*)d_in[10]};

    // workspace carve (256B aligned)
    char* p = (char*)d_ws;
    auto carve = [&](size_t bytes) {
        char* r = p;
        p += (bytes + 255) & ~(size_t)255;
        return r;
    };
    unsigned short* Xb = (unsigned short*)carve((size_t)N * 128 * 2);  // bf16 input plane
    unsigned short* Hb = (unsigned short*)carve((size_t)N * 128 * 2);  // bf16 hidden plane
    unsigned short* Fb = (unsigned short*)carve((size_t)N * 128 * 2);  // bf16 f plane
    unsigned short* Wt = (unsigned short*)carve((size_t)3 * 16384 * 2);
    float* el       = (float*)carve((size_t)N * 4 * 4);
    float* er       = (float*)carve((size_t)N * 4 * 4);
    int* deg        = (int*)carve((size_t)N * 4);
    int* rowstart   = (int*)carve((size_t)N * 4);
    int* cursor     = (int*)carve((size_t)N * 4);
    int* csrc       = (int*)carve((size_t)E * 4);
    int* bsum       = (int*)carve(256 * 4);

    // ---- CSR build (once; reused by all 3 layers) ----
    hipMemsetAsync(deg, 0, (size_t)N * 4, stream);
    k_hist<<<(E + 255) / 256, 256, 0, stream>>>(dst, deg, E);
    int nb = (N + 2047) / 2048;
    k_scan1<<<nb, 256, 0, stream>>>(deg, rowstart, bsum, N);
    k_scan2<<<1, 256, 0, stream>>>(bsum, nb);
    k_scan3<<<(N + 255) / 256, 256, 0, stream>>>(rowstart, cursor, bsum, N);
    k_scatter<<<(E + 255) / 256, 256, 0, stream>>>(src, dst, cursor, csrc, E);

    // ---- bf16 prep ----
    int n8 = N * 128 / 8;
    k_cvt<<<(n8 + 255) / 256, 256, 0, stream>>>((const float4*)x, (uint4*)Xb, n8);
    k_prep_w<<<(3 * 16384) / 256, 256, 0, stream>>>(Wm[0], Wm[1], Wm[2], Wt);

    // ---- 3 GAT layers ----
    int gb = (N + 127) / 128;
    k_gemm<<<gb, 256, 0, stream>>>(Xb, Wt, al[0], ar[0], Fb, el, er, N);
    k_aggr<1><<<(N + 3) / 4, 256, 0, stream>>>(rowstart, deg, csrc, el, er,
                                               (const unsigned*)Fb, Hb, N);
    k_gemm<<<gb, 256, 0, stream>>>(Hb, Wt + 16384, al[1], ar[1], Fb, el, er, N);
    k_aggr<1><<<(N + 3) / 4, 256, 0, stream>>>(rowstart, deg, csrc, el, er,
                                               (const unsigned*)Fb, Hb, N);
    k_gemm<<<gb, 256, 0, stream>>>(Hb, Wt + 32768, al[2], ar[2], Fb, el, er, N);
    k_aggr<0><<<(N + 3) / 4, 256, 0, stream>>>(rowstart, deg, csrc, el, er,
                                               (const unsigned*)Fb, d_out, N);
}

// Round 5
// 697.490 us; speedup vs baseline: 1.3623x; 1.0810x over previous
//
#include <hip/hip_runtime.h>
#include <math.h>

#define NEG_SLOPE 0.2f
#define NBUCK 512      // dst buckets of 256 nodes (N=100000 -> 391 used)
#define BCHUNK 4096    // edges per k_bin block

typedef __attribute__((ext_vector_type(8))) short short8;   // 8 bf16 = 4 VGPR (MFMA A/B frag)
typedef __attribute__((ext_vector_type(4))) float f32x4;    // MFMA C/D frag

__device__ __forceinline__ unsigned short bf16rne(float x) {
    unsigned u = __float_as_uint(x);
    u += 0x7fffu + ((u >> 16) & 1u);
    return (unsigned short)(u >> 16);
}
// pack two floats -> uint (x low16, y high16), RNE
__device__ __forceinline__ unsigned pack_bf2(float x, float y) {
    unsigned ux = __float_as_uint(x), uy = __float_as_uint(y);
    ux = (ux + 0x7fffu + ((ux >> 16) & 1u)) >> 16;
    uy = (uy + 0x7fffu + ((uy >> 16) & 1u)) & 0xffff0000u;
    return ux | uy;
}

// ---------------- fused front kernel: hist + x->bf16 + W->Wt bf16 ----------------

__global__ void k_front(const int* __restrict__ dst, int* __restrict__ deg, int E,
                        const float4* __restrict__ x, uint4* __restrict__ Xb, int n8,
                        const float* __restrict__ w0, const float* __restrict__ w1,
                        const float* __restrict__ w2, unsigned short* __restrict__ Wt,
                        int nbHist, int nbCvt) {
    int bb = blockIdx.x;
    if (bb < nbHist) {
        int e = bb * 256 + threadIdx.x;
        if (e < E) atomicAdd(&deg[dst[e]], 1);
    } else if (bb < nbHist + nbCvt) {
        int id = (bb - nbHist) * 256 + threadIdx.x;
        if (id < n8) {
            float4 a = x[id * 2], b = x[id * 2 + 1];
            uint4 o;
            o.x = pack_bf2(a.x, a.y);
            o.y = pack_bf2(a.z, a.w);
            o.z = pack_bf2(b.x, b.y);
            o.w = pack_bf2(b.z, b.w);
            Xb[id] = o;
        }
    } else {
        int id = (bb - nbHist - nbCvt) * 256 + threadIdx.x;   // 3*16384 ids
        int layer = id >> 14, rem = id & 16383;
        int k = rem >> 7, n = rem & 127;
        const float* W = (layer == 0) ? w0 : (layer == 1) ? w1 : w2;
        Wt[layer * 16384 + n * 128 + k] = bf16rne(W[k * 128 + n]);
    }
}

// ---------------- scans (rowstart from deg) ----------------

__global__ void k_scan1(const int* __restrict__ in, int* __restrict__ out,
                        int* __restrict__ bsum, int n) {
    __shared__ int sd[256];
    int t = threadIdx.x;
    int base = blockIdx.x * 2048 + t * 8;
    int v[8];
#pragma unroll
    for (int i = 0; i < 8; i++) { int idx = base + i; v[i] = (idx < n) ? in[idx] : 0; }
#pragma unroll
    for (int i = 1; i < 8; i++) v[i] += v[i - 1];
    sd[t] = v[7];
    __syncthreads();
    for (int s = 1; s < 256; s <<= 1) {
        int x = (t >= s) ? sd[t - s] : 0;
        __syncthreads();
        sd[t] += x;
        __syncthreads();
    }
    int off = (t > 0) ? sd[t - 1] : 0;
#pragma unroll
    for (int i = 0; i < 8; i++) {
        int idx = base + i;
        if (idx < n) out[idx] = off + (i > 0 ? v[i - 1] : 0);
    }
    if (t == 255) bsum[blockIdx.x] = sd[255];
}

__global__ void k_scan2(int* __restrict__ bsum, int nb) {
    __shared__ int sd[256];
    int t = threadIdx.x;
    sd[t] = (t < nb) ? bsum[t] : 0;
    __syncthreads();
    for (int s = 1; s < 256; s <<= 1) {
        int x = (t >= s) ? sd[t - s] : 0;
        __syncthreads();
        sd[t] += x;
        __syncthreads();
    }
    if (t < nb) bsum[t] = (t > 0) ? sd[t - 1] : 0;
}

// finalize rowstart; init cursor (= rowstart) and per-bucket claim cursors bcur
__global__ void k_scan3(int* __restrict__ out, int* __restrict__ cursor,
                        const int* __restrict__ bsum, int* __restrict__ bcur, int n) {
    int idx = blockIdx.x * 256 + threadIdx.x;
    if (idx < n) {
        int v = out[idx] + bsum[idx >> 11];
        out[idx] = v;
        cursor[idx] = v;
        if ((idx & 255) == 0) bcur[idx >> 8] = v;
    }
}

// ---------------- two-phase bucketed edge placement ----------------
// Phase 1: bin edges into 512 coarse buckets (256 dst nodes each). Packed
// word = src(17b)<<8 | dst_local(8b). Per-bucket runs claimed with one global
// atomic per (block,bucket) -> append writes are contiguous runs (~full lines)
// instead of fully random 4B scatters (R4's 105 MB -> ~7 MB write traffic).
__global__ __launch_bounds__(256) void k_bin(
    const int* __restrict__ src, const int* __restrict__ dst,
    int* __restrict__ bcur, unsigned* __restrict__ packed, int E) {
    __shared__ int cnt[NBUCK];
    __shared__ int gbase[NBUCK];
    for (int i = threadIdx.x; i < NBUCK; i += 256) cnt[i] = 0;
    __syncthreads();
    int e0 = blockIdx.x * BCHUNK;
    int n = min(BCHUNK, E - e0);
    for (int i = threadIdx.x; i < n; i += 256)
        atomicAdd(&cnt[dst[e0 + i] >> 8], 1);
    __syncthreads();
    for (int i = threadIdx.x; i < NBUCK; i += 256) {
        int c = cnt[i];
        gbase[i] = c ? atomicAdd(&bcur[i], c) : 0;
        cnt[i] = 0;
    }
    __syncthreads();
    for (int i = threadIdx.x; i < n; i += 256) {
        int d = dst[e0 + i];
        int b = d >> 8;
        int o = atomicAdd(&cnt[b], 1);
        packed[gbase[b] + o] = ((unsigned)src[e0 + i] << 8) | (unsigned)(d & 255);
    }
}

// Phase 2: one block per bucket; final csrc positions via per-node cursors.
// The bucket's csrc window (~16 KB) is written by exactly one block -> lines
// fully assemble in one L2 before eviction (no cross-XCD partial lines).
__global__ __launch_bounds__(256) void k_place(
    const unsigned* __restrict__ packed, const int* __restrict__ rowstart,
    const int* __restrict__ bcur, int* __restrict__ cursor,
    int* __restrict__ csrc, int N) {
    int b = blockIdx.x;
    int s0 = rowstart[b << 8];
    int s1 = bcur[b];
    for (int i = s0 + threadIdx.x; i < s1; i += 256) {
        unsigned p = packed[i];
        int d = (b << 8) | (int)(p & 255u);
        int pos = atomicAdd(&cursor[d], 1);
        csrc[pos] = (int)(p >> 8);
    }
}

// ---------------- MFMA GEMM + el/er epilogue ----------------
// f = A(Mx128 bf16) @ W(128x128, as Wt[n][k] bf16). 16x16x32 bf16 MFMA.
// Block = 4 waves x 32 rows = 128 rows; frags straight from global (Wt L2-hot).
// Epilogue: C-frags -> LDS bf16 (per-wave region, no barrier) -> coalesced F
// stores + el/er dot + lane-pair combine. Memory-bound (~55 MB).
__global__ __launch_bounds__(256) void k_gemm(
    const unsigned short* __restrict__ Ab,   // [M][128] bf16
    const unsigned short* __restrict__ Wt,   // [128 n][128 k] bf16
    const float* __restrict__ alv, const float* __restrict__ arv,
    unsigned short* __restrict__ Fb,         // [M][128] bf16
    float* __restrict__ el, float* __restrict__ er, int M) {
    __shared__ unsigned short cst[4][32][128];
    int t = threadIdx.x;
    int wv = t >> 6, l = t & 63;
    int l15 = l & 15, quad = l >> 4;
    int row0 = blockIdx.x * 128 + wv * 32;

    f32x4 acc[2][8];
#pragma unroll
    for (int mi = 0; mi < 2; mi++)
#pragma unroll
        for (int nt = 0; nt < 8; nt++)
            acc[mi][nt] = (f32x4){0.f, 0.f, 0.f, 0.f};

    int rA0 = min(row0 + l15, M - 1);
    int rA1 = min(row0 + 16 + l15, M - 1);
    const uint4* pA0 = (const uint4*)(Ab + (size_t)rA0 * 128) + quad;
    const uint4* pA1 = (const uint4*)(Ab + (size_t)rA1 * 128) + quad;
    const uint4* pW = (const uint4*)Wt;

#pragma unroll
    for (int ks = 0; ks < 4; ks++) {
        union { uint4 u; short8 s; } a0, a1, b[8];
        a0.u = pA0[ks * 4];
        a1.u = pA1[ks * 4];
#pragma unroll
        for (int nt = 0; nt < 8; nt++)
            b[nt].u = pW[(nt * 16 + l15) * 16 + quad + ks * 4];
#pragma unroll
        for (int nt = 0; nt < 8; nt++) {
            acc[0][nt] = __builtin_amdgcn_mfma_f32_16x16x32_bf16(a0.s, b[nt].s, acc[0][nt], 0, 0, 0);
            acc[1][nt] = __builtin_amdgcn_mfma_f32_16x16x32_bf16(a1.s, b[nt].s, acc[1][nt], 0, 0, 0);
        }
    }

    // C/D layout: col = lane&15, row = quad*4 + reg. Stage to LDS bf16.
#pragma unroll
    for (int mi = 0; mi < 2; mi++)
#pragma unroll
        for (int nt = 0; nt < 8; nt++)
#pragma unroll
            for (int r = 0; r < 4; r++)
                cst[wv][mi * 16 + quad * 4 + r][nt * 16 + l15] = bf16rne(acc[mi][nt][r]);
    // same-wave ds_write -> ds_read: lgkmcnt ordering only, no barrier needed.

    int rrow = l >> 1;            // 0..31
    int cb = (l & 1) * 64;        // col base: lane covers 64 cols of one row
    int grow = row0 + rrow;
    bool ok = grow < M;
    float pe[2] = {0.f, 0.f}, pr[2] = {0.f, 0.f};
#pragma unroll
    for (int i = 0; i < 8; i++) {
        uint4 v = *(const uint4*)&cst[wv][rrow][cb + i * 8];
        if (ok) ((uint4*)(Fb + (size_t)grow * 128 + cb))[i] = v;
        int hi = i >> 2;
        int c0 = cb + i * 8;
        unsigned uu[4] = {v.x, v.y, v.z, v.w};
#pragma unroll
        for (int q = 0; q < 4; q++) {
            float fa = __uint_as_float(uu[q] << 16);
            float fb = __uint_as_float(uu[q] & 0xffff0000u);
            pe[hi] += fa * alv[c0 + 2 * q] + fb * alv[c0 + 2 * q + 1];
            pr[hi] += fa * arv[c0 + 2 * q] + fb * arv[c0 + 2 * q + 1];
        }
    }
    float qe0 = __shfl_xor(pe[0], 1, 64), qe1 = __shfl_xor(pe[1], 1, 64);
    float qr0 = __shfl_xor(pr[0], 1, 64), qr1 = __shfl_xor(pr[1], 1, 64);
    if (((l & 1) == 0) && ok) {
        *(float4*)&el[(size_t)grow * 4] = make_float4(pe[0], pe[1], qe0, qe1);
        *(float4*)&er[(size_t)grow * 4] = make_float4(pr[0], pr[1], qr0, qr1);
    }
}

// ---------------- aggregation (wave per node, software-pipelined) ----------------
template <int OUT_BF16>
__global__ __launch_bounds__(256) void k_aggr(
    const int* __restrict__ rowstart, const int* __restrict__ deg,
    const int* __restrict__ csrc, const float* __restrict__ el,
    const float* __restrict__ er, const unsigned* __restrict__ FbU,
    void* __restrict__ outp, int N) {
    int w = blockIdx.x * 4 + (threadIdx.x >> 6);
    int lane = threadIdx.x & 63;
    if (w >= N) return;
    int h = lane >> 4;
    int start = rowstart[w], dg = deg[w];
    float er_h = er[w * 4 + h];
    float s_acc = 0.f, a0 = 0.f, a1 = 0.f;

    auto loadc = [&](int j, int* idx, unsigned* fv, float* ee) {
        if (j + 8 <= dg) {
#pragma unroll
            for (int u = 0; u < 8; u++) idx[u] = csrc[start + j + u];
#pragma unroll
            for (int u = 0; u < 8; u++) {
                fv[u] = FbU[(size_t)idx[u] * 64 + lane];
                ee[u] = el[idx[u] * 4 + h];
            }
        } else {
            int lim = dg - j;  // >= 1
#pragma unroll
            for (int u = 0; u < 8; u++) idx[u] = csrc[start + j + min(u, lim - 1)];
#pragma unroll
            for (int u = 0; u < 8; u++) {
                fv[u] = FbU[(size_t)idx[u] * 64 + lane];
                ee[u] = (u < lim) ? el[idx[u] * 4 + h] : -1e30f;
            }
        }
    };
    auto consume = [&](const unsigned* fv, const float* ee) {
#pragma unroll
        for (int u = 0; u < 8; u++) {
            float e = ee[u] + er_h;
            e = fmaxf(e, NEG_SLOPE * e);
            float p = __expf(e);
            s_acc += p;
            a0 += p * __uint_as_float(fv[u] << 16);
            a1 += p * __uint_as_float(fv[u] & 0xffff0000u);
        }
    };

    int ncc = (dg + 7) >> 3;
    int i0[8], i1[8];
    unsigned f0[8], f1[8];
    float e0[8], e1[8];
    if (ncc > 0) {
        loadc(0, i0, f0, e0);
        for (int c = 1; c < ncc; c++) {
            if (c & 1) { loadc(c << 3, i1, f1, e1); consume(f0, e0); }
            else       { loadc(c << 3, i0, f0, e0); consume(f1, e1); }
        }
        if (ncc & 1) consume(f0, e0); else consume(f1, e1);
    }

    float inv = 1.f / (s_acc + 1e-9f);
    float o0 = fmaxf(a0 * inv, 0.f);
    float o1 = fmaxf(a1 * inv, 0.f);
    if (OUT_BF16) {
        ((unsigned*)outp)[(size_t)w * 64 + lane] = pack_bf2(o0, o1);
    } else {
        ((float2*)outp)[(size_t)w * 64 + lane] = make_float2(o0, o1);
    }
}

// ---------------- launch ----------------

extern "C" void kernel_launch(void* const* d_in, const int* in_sizes, int n_in,
                              void* d_out, int out_size, void* d_ws, size_t ws_size,
                              hipStream_t stream) {
    const float* x = (const float*)d_in[0];
    const int* ei = (const int*)d_in[1];
    int N = in_sizes[0] / 128;       // 100000
    int E = in_sizes[1] / 2;         // 1600000
    const int* src = ei;
    const int* dst = ei + E;
    const float* Wm[3] = {(const float*)d_in[2], (const float*)d_in[5], (const float*)d_in[8]};
    const float* al[3] = {(const float*)d_in[3], (const float*)d_in[6], (const float*)d_in[9]};
    const float* ar[3] = {(const float*)d_in[4], (const float*)d_in[7], (const float*)d_in[10]};

    // workspace carve (256B aligned)
    char* p = (char*)d_ws;
    auto carve = [&](size_t bytes) {
        char* r = p;
        p += (bytes + 255) & ~(size_t)255;
        return r;
    };
    unsigned short* Xb = (unsigned short*)carve((size_t)N * 128 * 2);  // bf16 input plane
    unsigned short* Hb = (unsigned short*)carve((size_t)N * 128 * 2);  // bf16 hidden plane
    unsigned short* Fb = (unsigned short*)carve((size_t)N * 128 * 2);  // bf16 f plane
    unsigned short* Wt = (unsigned short*)carve((size_t)3 * 16384 * 2);
    float* el       = (float*)carve((size_t)N * 4 * 4);
    float* er       = (float*)carve((size_t)N * 4 * 4);
    int* deg        = (int*)carve((size_t)N * 4);
    int* rowstart   = (int*)carve((size_t)(N + 1) * 4);
    int* cursor     = (int*)carve((size_t)N * 4);
    int* csrc       = (int*)carve((size_t)E * 4);
    unsigned* packed= (unsigned*)carve((size_t)E * 4);
    int* bcur       = (int*)carve((size_t)NBUCK * 4);
    int* bsum       = (int*)carve(256 * 4);

    // ---- CSR build (once; reused by all 3 layers) ----
    hipMemsetAsync(deg, 0, (size_t)N * 4, stream);
    int nbHist = (E + 255) / 256;
    int n8 = N * 128 / 8;
    int nbCvt = (n8 + 255) / 256;
    int nbPrep = (3 * 16384) / 256;
    k_front<<<nbHist + nbCvt + nbPrep, 256, 0, stream>>>(
        dst, deg, E, (const float4*)x, (uint4*)Xb, n8,
        Wm[0], Wm[1], Wm[2], Wt, nbHist, nbCvt);
    int nb = (N + 2047) / 2048;
    k_scan1<<<nb, 256, 0, stream>>>(deg, rowstart, bsum, N);
    k_scan2<<<1, 256, 0, stream>>>(bsum, nb);
    k_scan3<<<(N + 255) / 256, 256, 0, stream>>>(rowstart, cursor, bsum, bcur, N);
    k_bin<<<(E + BCHUNK - 1) / BCHUNK, 256, 0, stream>>>(src, dst, bcur, packed, E);
    k_place<<<(N + 255) / 256, 256, 0, stream>>>(packed, rowstart, bcur, cursor, csrc, N);

    // ---- 3 GAT layers ----
    int gb = (N + 127) / 128;
    k_gemm<<<gb, 256, 0, stream>>>(Xb, Wt, al[0], ar[0], Fb, el, er, N);
    k_aggr<1><<<(N + 3) / 4, 256, 0, stream>>>(rowstart, deg, csrc, el, er,
                                               (const unsigned*)Fb, Hb, N);
    k_gemm<<<gb, 256, 0, stream>>>(Hb, Wt + 16384, al[1], ar[1], Fb, el, er, N);
    k_aggr<1><<<(N + 3) / 4, 256, 0, stream>>>(rowstart, deg, csrc, el, er,
                                               (const unsigned*)Fb, Hb, N);
    k_gemm<<<gb, 256, 0, stream>>>(Hb, Wt + 32768, al[2], ar[2], Fb, el, er, N);
    k_aggr<0><<<(N + 3) / 4, 256, 0, stream>>>(rowstart, deg, csrc, el, er,
                                               (const unsigned*)Fb, d_out, N);
}

// Round 6
// 551.175 us; speedup vs baseline: 1.7239x; 1.2655x over previous
//
#include <hip/hip_runtime.h>
#include <math.h>

#define NEG_SLOPE 0.2f
#define NBUCK 512      // dst buckets of 256 nodes
#define BHCHUNK 8192   // edges per histogram block
#define BCHUNK 4096    // edges per k_bin block

typedef __attribute__((ext_vector_type(8))) short short8;   // 8 bf16 (MFMA A/B frag)
typedef __attribute__((ext_vector_type(4))) float f32x4;    // MFMA C/D frag

__device__ __forceinline__ unsigned short bf16rne(float x) {
    unsigned u = __float_as_uint(x);
    u += 0x7fffu + ((u >> 16) & 1u);
    return (unsigned short)(u >> 16);
}
__device__ __forceinline__ unsigned pack_bf2(float x, float y) {
    unsigned ux = __float_as_uint(x), uy = __float_as_uint(y);
    ux = (ux + 0x7fffu + ((ux >> 16) & 1u)) >> 16;
    uy = (uy + 0x7fffu + ((uy >> 16) & 1u)) & 0xffff0000u;
    return ux | uy;
}

// ---------------- fused front: bucket-hist + x->bf16 + W->Wt ----------------
__global__ __launch_bounds__(256) void k_front(
    const int* __restrict__ dst, int* __restrict__ bcnt, int E,
    const float4* __restrict__ x, uint4* __restrict__ Xb, int n8,
    const float* __restrict__ w0, const float* __restrict__ w1,
    const float* __restrict__ w2, unsigned short* __restrict__ Wt,
    int nbB, int nbCvt) {
    __shared__ int cnt[NBUCK];
    int bb = blockIdx.x, t = threadIdx.x;
    if (bb < nbB) {
        for (int i = t; i < NBUCK; i += 256) cnt[i] = 0;
        __syncthreads();
        int e0 = bb * BHCHUNK;
        int n = min(BHCHUNK, E - e0);
        for (int i = t; i < n; i += 256) atomicAdd(&cnt[dst[e0 + i] >> 8], 1);
        __syncthreads();
        for (int i = t; i < NBUCK; i += 256)
            if (cnt[i]) atomicAdd(&bcnt[i], cnt[i]);
    } else if (bb < nbB + nbCvt) {
        int id = (bb - nbB) * 256 + t;
        if (id < n8) {
            float4 a = x[id * 2], b = x[id * 2 + 1];
            uint4 o;
            o.x = pack_bf2(a.x, a.y);
            o.y = pack_bf2(a.z, a.w);
            o.z = pack_bf2(b.x, b.y);
            o.w = pack_bf2(b.z, b.w);
            Xb[id] = o;
        }
    } else {
        int id = (bb - nbB - nbCvt) * 256 + t;    // 3*16384 ids
        int layer = id >> 14, rem = id & 16383;
        int k = rem >> 7, n = rem & 127;
        const float* W = (layer == 0) ? w0 : (layer == 1) ? w1 : w2;
        Wt[layer * 16384 + n * 128 + k] = bf16rne(W[k * 128 + n]);
    }
}

// ---------------- bucket scan (one block, 512 threads) ----------------
__global__ void k_bscan(const int* __restrict__ bcnt, int* __restrict__ bbase,
                        int* __restrict__ bcur, int* __restrict__ rowstart,
                        int N, int E) {
    __shared__ int sd[NBUCK];
    int t = threadIdx.x;
    int c = bcnt[t];
    sd[t] = c;
    __syncthreads();
    for (int s = 1; s < NBUCK; s <<= 1) {
        int x = (t >= s) ? sd[t - s] : 0;
        __syncthreads();
        sd[t] += x;
        __syncthreads();
    }
    int excl = sd[t] - c;
    bbase[t] = excl;
    bcur[t] = excl;
    if (t == NBUCK - 1) bbase[NBUCK] = excl + c;   // == E
    if (t == 0) rowstart[N] = E;
}

// ---------------- bin edges into buckets (contiguous packed runs) ----------------
__global__ __launch_bounds__(256) void k_bin(
    const int* __restrict__ src, const int* __restrict__ dst,
    int* __restrict__ bcur, unsigned* __restrict__ packed, int E) {
    __shared__ int cnt[NBUCK];
    __shared__ int gbase[NBUCK];
    for (int i = threadIdx.x; i < NBUCK; i += 256) cnt[i] = 0;
    __syncthreads();
    int e0 = blockIdx.x * BCHUNK;
    int n = min(BCHUNK, E - e0);
    for (int i = threadIdx.x; i < n; i += 256)
        atomicAdd(&cnt[dst[e0 + i] >> 8], 1);
    __syncthreads();
    for (int i = threadIdx.x; i < NBUCK; i += 256) {
        int c = cnt[i];
        gbase[i] = c ? atomicAdd(&bcur[i], c) : 0;
        cnt[i] = 0;
    }
    __syncthreads();
    for (int i = threadIdx.x; i < n; i += 256) {
        int d = dst[e0 + i];
        int b = d >> 8;
        int o = atomicAdd(&cnt[b], 1);
        packed[gbase[b] + o] = ((unsigned)src[e0 + i] << 8) | (unsigned)(d & 255);
    }
}

// ---------------- per-bucket: node hist + scan -> rowstart; place via LDS cursors ----
// cpack entry = (dst_local<<17) | src  (src < 2^17).
__global__ __launch_bounds__(256) void k_place2(
    const unsigned* __restrict__ packed, const int* __restrict__ bbase,
    int* __restrict__ rowstart, unsigned* __restrict__ cpack, int N) {
    __shared__ int cnt[256], sd[256], lcur[256];
    int b = blockIdx.x, t = threadIdx.x;
    int base = bbase[b], end = bbase[b + 1];
    cnt[t] = 0;
    __syncthreads();
    for (int i = base + t; i < end; i += 256)
        atomicAdd(&cnt[packed[i] & 255u], 1);
    __syncthreads();
    sd[t] = cnt[t];
    __syncthreads();
    for (int s = 1; s < 256; s <<= 1) {
        int x = (t >= s) ? sd[t - s] : 0;
        __syncthreads();
        sd[t] += x;
        __syncthreads();
    }
    int excl = sd[t] - cnt[t];
    int gid = (b << 8) + t;
    if (gid < N) rowstart[gid] = base + excl;
    lcur[t] = base + excl;
    __syncthreads();
    for (int i = base + t; i < end; i += 256) {
        unsigned p = packed[i];
        unsigned dl = p & 255u;
        int pos = atomicAdd(&lcur[dl], 1);
        cpack[pos] = (dl << 17) | (p >> 8);
    }
}

// ---------------- MFMA GEMM + el/er epilogue (unchanged) ----------------
__global__ __launch_bounds__(256) void k_gemm(
    const unsigned short* __restrict__ Ab,   // [M][128] bf16
    const unsigned short* __restrict__ Wt,   // [128 n][128 k] bf16
    const float* __restrict__ alv, const float* __restrict__ arv,
    unsigned short* __restrict__ Fb,         // [M][128] bf16
    float* __restrict__ el, float* __restrict__ er, int M) {
    __shared__ unsigned short cst[4][32][128];
    int t = threadIdx.x;
    int wv = t >> 6, l = t & 63;
    int l15 = l & 15, quad = l >> 4;
    int row0 = blockIdx.x * 128 + wv * 32;

    f32x4 acc[2][8];
#pragma unroll
    for (int mi = 0; mi < 2; mi++)
#pragma unroll
        for (int nt = 0; nt < 8; nt++)
            acc[mi][nt] = (f32x4){0.f, 0.f, 0.f, 0.f};

    int rA0 = min(row0 + l15, M - 1);
    int rA1 = min(row0 + 16 + l15, M - 1);
    const uint4* pA0 = (const uint4*)(Ab + (size_t)rA0 * 128) + quad;
    const uint4* pA1 = (const uint4*)(Ab + (size_t)rA1 * 128) + quad;
    const uint4* pW = (const uint4*)Wt;

#pragma unroll
    for (int ks = 0; ks < 4; ks++) {
        union { uint4 u; short8 s; } a0, a1, b[8];
        a0.u = pA0[ks * 4];
        a1.u = pA1[ks * 4];
#pragma unroll
        for (int nt = 0; nt < 8; nt++)
            b[nt].u = pW[(nt * 16 + l15) * 16 + quad + ks * 4];
#pragma unroll
        for (int nt = 0; nt < 8; nt++) {
            acc[0][nt] = __builtin_amdgcn_mfma_f32_16x16x32_bf16(a0.s, b[nt].s, acc[0][nt], 0, 0, 0);
            acc[1][nt] = __builtin_amdgcn_mfma_f32_16x16x32_bf16(a1.s, b[nt].s, acc[1][nt], 0, 0, 0);
        }
    }

#pragma unroll
    for (int mi = 0; mi < 2; mi++)
#pragma unroll
        for (int nt = 0; nt < 8; nt++)
#pragma unroll
            for (int r = 0; r < 4; r++)
                cst[wv][mi * 16 + quad * 4 + r][nt * 16 + l15] = bf16rne(acc[mi][nt][r]);

    int rrow = l >> 1;
    int cb = (l & 1) * 64;
    int grow = row0 + rrow;
    bool ok = grow < M;
    float pe[2] = {0.f, 0.f}, pr[2] = {0.f, 0.f};
#pragma unroll
    for (int i = 0; i < 8; i++) {
        uint4 v = *(const uint4*)&cst[wv][rrow][cb + i * 8];
        if (ok) ((uint4*)(Fb + (size_t)grow * 128 + cb))[i] = v;
        int hi = i >> 2;
        int c0 = cb + i * 8;
        unsigned uu[4] = {v.x, v.y, v.z, v.w};
#pragma unroll
        for (int q = 0; q < 4; q++) {
            float fa = __uint_as_float(uu[q] << 16);
            float fb = __uint_as_float(uu[q] & 0xffff0000u);
            pe[hi] += fa * alv[c0 + 2 * q] + fb * alv[c0 + 2 * q + 1];
            pr[hi] += fa * arv[c0 + 2 * q] + fb * arv[c0 + 2 * q + 1];
        }
    }
    float qe0 = __shfl_xor(pe[0], 1, 64), qe1 = __shfl_xor(pe[1], 1, 64);
    float qr0 = __shfl_xor(pr[0], 1, 64), qr1 = __shfl_xor(pr[1], 1, 64);
    if (((l & 1) == 0) && ok) {
        *(float4*)&el[(size_t)grow * 4] = make_float4(pe[0], pe[1], qe0, qe1);
        *(float4*)&er[(size_t)grow * 4] = make_float4(pr[0], pr[1], qr0, qr1);
    }
}

// ---------------- edge attention: p = exp(leaky(el[s]+er[d])) once per edge ----------
// Block per bucket; er slab (4 KB) L1-hot; pw writes coalesced full lines.
__global__ __launch_bounds__(256) void k_edge(
    const unsigned* __restrict__ cpack, const int* __restrict__ bbase,
    const float4* __restrict__ el4, const float4* __restrict__ er4,
    float4* __restrict__ pw4) {
    int b = blockIdx.x, t = threadIdx.x;
    int base = bbase[b], end = bbase[b + 1];
    for (int i = base + t; i < end; i += 256) {
        unsigned w = cpack[i];
        int s = (int)(w & 0x1ffffu);
        int d = (b << 8) + (int)(w >> 17);
        float4 l = el4[s], r = er4[d];
        float4 o;
        float e;
        e = l.x + r.x; e = fmaxf(e, NEG_SLOPE * e); o.x = __expf(e);
        e = l.y + r.y; e = fmaxf(e, NEG_SLOPE * e); o.y = __expf(e);
        e = l.z + r.z; e = fmaxf(e, NEG_SLOPE * e); o.z = __expf(e);
        e = l.w + r.w; e = fmaxf(e, NEG_SLOPE * e); o.w = __expf(e);
        pw4[i] = o;
    }
}

// ---------------- aggregation: 2 nodes/wave, 32 lanes x 4 features each ----------
// Lane l32 owns features [l32*4, l32*4+4) (uint2 of packed bf16, head = l32>>3).
// p pre-computed in pw (fp32). Ping-pong 8-edge chunks; chunks < minfull take the
// unmasked path (wave-uniform branch), the rest clamp indices and zero p.
template <int OUT_BF16>
__global__ __launch_bounds__(256) void k_aggr(
    const int* __restrict__ rowstart, const unsigned* __restrict__ cpack,
    const float* __restrict__ pw, const unsigned* __restrict__ FbU,
    void* __restrict__ outp, int N, int E) {
    int lane = threadIdx.x & 63;
    int half = lane >> 5;
    int l32 = lane & 31;
    int w = blockIdx.x * 8 + ((threadIdx.x >> 6) << 1) + half;
    bool active = w < N;
    int wc = active ? w : N - 1;
    int start = rowstart[wc];
    int dg = active ? (rowstart[wc + 1] - start) : 0;
    int h = l32 >> 3;
    int laneu = l32 * 2;           // uint offset within F row

    float s_acc = 0.f;
    float a0 = 0.f, a1 = 0.f, a2 = 0.f, a3 = 0.f;

    int ncc = (dg + 7) >> 3;
    int nccmax = max(ncc, __shfl_xor(ncc, 32, 64));
    int full = dg >> 3;
    int minfull = min(full, __shfl_xor(full, 32, 64));   // wave-uniform

    auto loadc = [&](int c, uint2* fb, float* pb) {
        int j = c << 3;
        if (c < minfull) {
#pragma unroll
            for (int u = 0; u < 8; u++) {
                int e = start + j + u;
                unsigned cp = cpack[e];
                int s = (int)(cp & 0x1ffffu);
                fb[u] = *(const uint2*)(FbU + (size_t)s * 64 + laneu);
                pb[u] = pw[(size_t)e * 4 + h];
            }
        } else {
#pragma unroll
            for (int u = 0; u < 8; u++) {
                int jj = j + u;
                int e = min(start + max(min(jj, dg - 1), 0), E - 1);
                unsigned cp = cpack[e];
                int s = (int)(cp & 0x1ffffu);
                fb[u] = *(const uint2*)(FbU + (size_t)s * 64 + laneu);
                float pv = pw[(size_t)e * 4 + h];
                pb[u] = (jj < dg) ? pv : 0.f;
            }
        }
    };
    auto consume = [&](const uint2* fb, const float* pb) {
#pragma unroll
        for (int u = 0; u < 8; u++) {
            float p = pb[u];
            s_acc += p;
            a0 += p * __uint_as_float(fb[u].x << 16);
            a1 += p * __uint_as_float(fb[u].x & 0xffff0000u);
            a2 += p * __uint_as_float(fb[u].y << 16);
            a3 += p * __uint_as_float(fb[u].y & 0xffff0000u);
        }
    };

    uint2 f0[8], f1[8];
    float p0[8], p1[8];
    if (nccmax > 0) {
        loadc(0, f0, p0);
        for (int c = 1; c < nccmax; c++) {
            if (c & 1) { loadc(c, f1, p1); consume(f0, p0); }
            else       { loadc(c, f0, p0); consume(f1, p1); }
        }
        if (nccmax & 1) consume(f0, p0); else consume(f1, p1);
    }

    if (!active) return;
    float inv = 1.f / (s_acc + 1e-9f);
    float o0 = fmaxf(a0 * inv, 0.f);
    float o1 = fmaxf(a1 * inv, 0.f);
    float o2 = fmaxf(a2 * inv, 0.f);
    float o3 = fmaxf(a3 * inv, 0.f);
    if (OUT_BF16) {
        uint2 pk;
        pk.x = pack_bf2(o0, o1);
        pk.y = pack_bf2(o2, o3);
        *(uint2*)(((unsigned*)outp) + (size_t)w * 64 + laneu) = pk;
    } else {
        ((float4*)outp)[(size_t)w * 32 + l32] = make_float4(o0, o1, o2, o3);
    }
}

// ---------------- launch ----------------

extern "C" void kernel_launch(void* const* d_in, const int* in_sizes, int n_in,
                              void* d_out, int out_size, void* d_ws, size_t ws_size,
                              hipStream_t stream) {
    const float* x = (const float*)d_in[0];
    const int* ei = (const int*)d_in[1];
    int N = in_sizes[0] / 128;       // 100000
    int E = in_sizes[1] / 2;         // 1600000
    const int* src = ei;
    const int* dst = ei + E;
    const float* Wm[3] = {(const float*)d_in[2], (const float*)d_in[5], (const float*)d_in[8]};
    const float* al[3] = {(const float*)d_in[3], (const float*)d_in[6], (const float*)d_in[9]};
    const float* ar[3] = {(const float*)d_in[4], (const float*)d_in[7], (const float*)d_in[10]};

    char* p = (char*)d_ws;
    auto carve = [&](size_t bytes) {
        char* r = p;
        p += (bytes + 255) & ~(size_t)255;
        return r;
    };
    unsigned short* Xb = (unsigned short*)carve((size_t)N * 128 * 2);
    unsigned short* Hb = (unsigned short*)carve((size_t)N * 128 * 2);
    unsigned short* Fb = (unsigned short*)carve((size_t)N * 128 * 2);
    unsigned short* Wt = (unsigned short*)carve((size_t)3 * 16384 * 2);
    float* el       = (float*)carve((size_t)N * 4 * 4);
    float* er       = (float*)carve((size_t)N * 4 * 4);
    float* pw       = (float*)carve((size_t)E * 4 * 4);
    int* rowstart   = (int*)carve((size_t)(N + 1) * 4);
    unsigned* cpack = (unsigned*)carve((size_t)E * 4);
    unsigned* packed= (unsigned*)carve((size_t)E * 4);
    int* bcnt       = (int*)carve((size_t)NBUCK * 4);
    int* bbase      = (int*)carve((size_t)(NBUCK + 1) * 4);
    int* bcur       = (int*)carve((size_t)NBUCK * 4);

    int NBUSED = (N + 255) >> 8;     // 391

    // ---- CSR build (once) ----
    hipMemsetAsync(bcnt, 0, NBUCK * 4, stream);
    int nbB = (E + BHCHUNK - 1) / BHCHUNK;
    int n8 = N * 128 / 8;
    int nbCvt = (n8 + 255) / 256;
    int nbPrep = (3 * 16384) / 256;
    k_front<<<nbB + nbCvt + nbPrep, 256, 0, stream>>>(
        dst, bcnt, E, (const float4*)x, (uint4*)Xb, n8,
        Wm[0], Wm[1], Wm[2], Wt, nbB, nbCvt);
    k_bscan<<<1, NBUCK, 0, stream>>>(bcnt, bbase, bcur, rowstart, N, E);
    k_bin<<<(E + BCHUNK - 1) / BCHUNK, 256, 0, stream>>>(src, dst, bcur, packed, E);
    k_place2<<<NBUSED, 256, 0, stream>>>(packed, bbase, rowstart, cpack, N);

    // ---- 3 GAT layers ----
    int gb = (N + 127) / 128;
    int ab = (N + 7) / 8;
    k_gemm<<<gb, 256, 0, stream>>>(Xb, Wt, al[0], ar[0], Fb, el, er, N);
    k_edge<<<NBUSED, 256, 0, stream>>>(cpack, bbase, (const float4*)el, (const float4*)er,
                                       (float4*)pw);
    k_aggr<1><<<ab, 256, 0, stream>>>(rowstart, cpack, pw, (const unsigned*)Fb, Hb, N, E);

    k_gemm<<<gb, 256, 0, stream>>>(Hb, Wt + 16384, al[1], ar[1], Fb, el, er, N);
    k_edge<<<NBUSED, 256, 0, stream>>>(cpack, bbase, (const float4*)el, (const float4*)er,
                                       (float4*)pw);
    k_aggr<1><<<ab, 256, 0, stream>>>(rowstart, cpack, pw, (const unsigned*)Fb, Hb, N, E);

    k_gemm<<<gb, 256, 0, stream>>>(Hb, Wt + 32768, al[2], ar[2], Fb, el, er, N);
    k_edge<<<NBUSED, 256, 0, stream>>>(cpack, bbase, (const float4*)el, (const float4*)er,
                                       (float4*)pw);
    k_aggr<0><<<ab, 256, 0, stream>>>(rowstart, cpack, pw, (const unsigned*)Fb, d_out, N, E);
}